// Round 9
// baseline (3498.902 us; speedup 1.0000x reference)
//
#include <hip/hip_runtime.h>

#define LL 12
#define BB 8
#define HH 12
#define EE 768
#define DD 64
#define SS 1024
#define VV 50257
#define E3 2304
#define E4 3072
#define GRID_ 1024
#define N4HALF 18874368ull   // float4 per KV buffer
#define SL 4718592ull        // per-group copy slice (2*N4HALF/8)
#define SPC 32               // unsigned words per 128B cacheline
#define CROWS 72
#define NCHU 8               // covers kv <= 576

typedef float f4_ __attribute__((ext_vector_type(4)));

__device__ __forceinline__ float gelu_tanh(float v) {
    float c = 0.7978845608028654f * (v + 0.044715f * v * v * v);
    return 0.5f * v * (1.0f + tanhf(c));
}

// ---- agent-scope atomics (cross-XCD; registration/final only) ----
__device__ __forceinline__ unsigned ld_at(unsigned* p) {
    return __hip_atomic_load(p, __ATOMIC_RELAXED, __HIP_MEMORY_SCOPE_AGENT);
}
__device__ __forceinline__ unsigned add_at(unsigned* p, unsigned v) {
    return __hip_atomic_fetch_add(p, v, __ATOMIC_RELAXED, __HIP_MEMORY_SCOPE_AGENT);
}
__device__ __forceinline__ void st_sys(float* p, float v) {
    __hip_atomic_store(p, v, __ATOMIC_RELAXED, __HIP_MEMORY_SCOPE_SYSTEM);
}

// ---- XCD-L2-local atomic add-with-return (no sc1 -> local L2) ----
__device__ __forceinline__ unsigned l2_add(unsigned* p, unsigned v) {
    unsigned old;
    asm volatile("s_waitcnt vmcnt(0)\n\t"
                 "global_atomic_add %0, %1, %2, off sc0\n\t"
                 "s_waitcnt vmcnt(0)"
                 : "=&v"(old) : "v"(p), "v"(v) : "memory");
    return old;
}

__device__ __forceinline__ void l1_inv() {
    asm volatile("buffer_inv\ns_waitcnt vmcnt(0)" ::: "memory");
}

// group barrier: L2-local arrival counter + 4 mirrored flags
__device__ __forceinline__ void gbar(unsigned* gq, unsigned rank, unsigned c, unsigned nbar) {
    __syncthreads();
    if (threadIdx.x == 0) {
        unsigned old = l2_add(gq, 1u);
        if (old + 1u == c * nbar) {
#pragma unroll
            for (int k = 0; k < 4; k++) l2_add(gq + (4 + k) * SPC, 1u);
        } else {
            unsigned* f = gq + (4 + (rank & 3u)) * SPC;
            while (l2_add(f, 0u) < nbar) __builtin_amdgcn_s_sleep(4);
        }
    }
    __syncthreads();
    l1_inv();
}

// registration barrier over all blocks (agent scope, used once)
__device__ __forceinline__ void gbar_all(unsigned* sub) {
    __syncthreads();
    if (threadIdx.x == 0) {
        add_at(sub + (blockIdx.x & 3) * SPC, 1u);
        while (ld_at(sub) + ld_at(sub + SPC) + ld_at(sub + 2 * SPC) + ld_at(sub + 3 * SPC) < GRID_)
            __builtin_amdgcn_s_sleep(8);
    }
    __syncthreads();
    l1_inv();
}

// hierarchical final barrier: XCD-local arrival, 8 agent ops total
__device__ __forceinline__ void gbar_final(unsigned* fin, unsigned g, unsigned sg) {
    unsigned* loc = fin + g * SPC;
    unsigned* locf = fin + (8 + g) * SPC;
    unsigned* gc = fin + 16 * SPC;
    unsigned* gf = fin + 17 * SPC;
    __syncthreads();
    if (threadIdx.x == 0) {
        unsigned a = l2_add(loc, 1u);
        if (a + 1u == sg) {
            unsigned r = add_at(gc, sg);
            if (r + sg == GRID_) add_at(gf, 1u);
            else while (ld_at(gf) == 0u) __builtin_amdgcn_s_sleep(8);
            l2_add(locf, 1u);
        } else {
            while (l2_add(locf, 0u) == 0u) __builtin_amdgcn_s_sleep(4);
        }
    }
    __syncthreads();
    l1_inv();
}

// LN of (h1+h2) row (768) -> xl[0..768)
__device__ __forceinline__ void ln_row(const float* __restrict__ h1, const float* __restrict__ h2,
                                       const float* __restrict__ gg, const float* __restrict__ bb,
                                       float* xl, float* red, float* bcv) {
    int t = threadIdx.x;
    float v0 = h1[t] + h2[t];
    float v1 = h1[t + 256] + h2[t + 256];
    float v2 = h1[t + 512] + h2[t + 512];
    float s = v0 + v1 + v2, ss = v0 * v0 + v1 * v1 + v2 * v2;
#pragma unroll
    for (int m = 32; m >= 1; m >>= 1) { s += __shfl_xor(s, m); ss += __shfl_xor(ss, m); }
    int w = t >> 6;
    if ((t & 63) == 0) { red[w] = s; red[8 + w] = ss; }
    __syncthreads();
    if (t == 0) {
        float S = red[0] + red[1] + red[2] + red[3];
        float Q = red[8] + red[9] + red[10] + red[11];
        float mu = S * (1.f / EE);
        bcv[0] = mu;
        bcv[1] = rsqrtf(Q * (1.f / EE) - mu * mu + 1e-5f);
    }
    __syncthreads();
    float mu = bcv[0], rs = bcv[1];
    xl[t] = (v0 - mu) * rs * gg[t] + bb[t];
    xl[t + 256] = (v1 - mu) * rs * gg[t + 256] + bb[t + 256];
    xl[t + 512] = (v2 - mu) * rs * gg[t + 512] + bb[t + 512];
    __syncthreads();
}

// NC output cols, full-K dot (streaming nt weight loads, unrolled)
template <int NC>
__device__ __forceinline__ void gemmN(const float* xl, int K, const float* __restrict__ W, int ldw,
                                      const float* __restrict__ bias, float* __restrict__ out,
                                      int c0, float* red) {
    constexpr int NS = 256 / NC;
    int t = threadIdx.x;
    int cc = c0 + (t % NC), ks = t / NC;
    int kl = K / NS;
    const float* Wp = W + (size_t)(ks * kl) * ldw + cc;
    const float* xp = xl + ks * kl;
    float acc = 0.f;
#pragma unroll 8
    for (int e = 0; e < kl; e++) acc += xp[e] * __builtin_nontemporal_load(Wp + (size_t)e * ldw);
    red[t] = acc; __syncthreads();
    if (t < NC) {
        float a = bias[c0 + t];
#pragma unroll
        for (int k2 = 0; k2 < NS; k2++) a += red[k2 * NC + t];
        out[c0 + t] = a;
    }
    __syncthreads();
}

__global__ __launch_bounds__(256, 4) void k_all(
    const int* __restrict__ ids, const int* __restrict__ posp,
    const float* __restrict__ past_k, const float* __restrict__ past_v,
    const float* __restrict__ wte, const float* __restrict__ wpe,
    const float* __restrict__ ln1g, const float* __restrict__ ln1b,
    const float* __restrict__ aw, const float* __restrict__ ab,
    const float* __restrict__ pw, const float* __restrict__ pb,
    const float* __restrict__ ln2g, const float* __restrict__ ln2b,
    const float* __restrict__ fw, const float* __restrict__ fb,
    const float* __restrict__ fpw, const float* __restrict__ fpb,
    const float* __restrict__ lnfg, const float* __restrict__ lnfb,
    float* __restrict__ logits, float* __restrict__ okeys, float* __restrict__ ovals,
    unsigned* __restrict__ ctrl,
    float* __restrict__ hB, float* __restrict__ hA, float* __restrict__ tmlp,
    float* __restrict__ tproj, float* __restrict__ qkv, float* __restrict__ fcbuf,
    float* __restrict__ pm, float* __restrict__ psum, float* __restrict__ po,
    float* __restrict__ xf) {

    int t = threadIdx.x;
    int pos = *posp, kv = pos + 1;

    __shared__ __align__(16) float xl[6144];
    __shared__ float red[256];
    __shared__ float bcv[4];
    __shared__ unsigned shu[4];

    // ---- registration: group = physical XCD ----
    if (t == 0) {
        unsigned xcc;
        asm volatile("s_getreg_b32 %0, hwreg(HW_REG_XCC_ID)" : "=s"(xcc));
        unsigned gg = xcc & 7u;
        shu[0] = gg;
        shu[1] = add_at(ctrl + gg * SPC, 1u);
    }
    __syncthreads();
    unsigned g = shu[0], rank = shu[1];
    gbar_all(ctrl + 8 * SPC);
    if (t == 0) shu[2] = ld_at(ctrl + g * SPC);
    __syncthreads();
    unsigned sg = shu[2];
    unsigned c = sg - sg / 4;
    if (c == 0 || c > sg) c = sg;

    if (rank < c) {
        // ================= compute blocks =================
        unsigned* gq = ctrl + 1024 + g * 8 * SPC;
        unsigned nbar = 0;
        float* hBg = hB + g * EE;
        float* hAg = hA + g * EE;
        float* tmlpg = tmlp + g * EE;
        float* tprojg = tproj + g * EE;
        float* qkvg = qkv + g * E3;
        float* fcbufg = fcbuf + g * E4;

        // prologue: embed row g (distributed), tmlp row = 0
        for (unsigned i = rank; i < 96; i += c) {
            if (t < 8) {
                int e = i * 8 + t;
                hBg[e] = wte[(size_t)ids[g] * EE + e] + wpe[(size_t)pos * EE + e];
                tmlpg[e] = 0.f;
            }
        }
        nbar++; gbar(gq, rank, c, nbar);

        for (int l = 0; l < LL; l++) {
            const float* aw_l = aw + (size_t)l * EE * E3;
            const float* ab_l = ab + (size_t)l * E3;
            const float* pw_l = pw + (size_t)l * EE * EE;
            const float* pb_l = pb + (size_t)l * EE;
            const float* fw_l = fw + (size_t)l * EE * E4;
            const float* fb_l = fb + (size_t)l * E4;
            const float* fpw_l = fpw + (size_t)l * E4 * EE;
            const float* fpb_l = fpb + (size_t)l * EE;

            // ---- Ph0: x=LN1(hB+tmlp); qkv = x@aw + ab ; hA=hB+tmlp (distributed)
            ln_row(hBg, tmlpg, ln1g + l * EE, ln1b + l * EE, xl, red, bcv);
            for (unsigned u = rank; u < 72; u += c)
                gemmN<32>(xl, EE, aw_l, E3, ab_l, qkvg, u * 32, red);
            for (unsigned i = rank; i < 96; i += c)
                if (t < 8) { int e = i * 8 + t; hAg[e] = hBg[e] + tmlpg[e]; }
            nbar++; gbar(gq, rank, c, nbar);

            // ---- Ph1: attention partials (+ write new K/V row), 96 units
            for (unsigned u = rank; u < HH * NCHU; u += c) {
                int hh = u >> 3, ch = u & 7;
                int j0 = ch * CROWS;
                int idx = (g * HH + hh) * NCHU + ch;
                if (j0 >= kv) { if (t == 0) psum[idx] = 0.f; continue; }
                const size_t off = ((size_t)l * BB * HH + g * HH + hh) * SS * DD;
                const float* Kc = past_k + off;
                const float* Vc = past_v + off;
                const float* qn = qkvg + hh * DD;
                const float* kn = qn + EE;
                const float* vn = qn + 2 * EE;
                float* qs = xl;
                float* sv = xl + 64;
                if (t < DD) qs[t] = qn[t];
                __syncthreads();

                if (t < 2 * CROWS) {
                    int row = t >> 1, half = t & 1;
                    int j = j0 + row;
                    float sj = 0.f;
                    if (j < kv) {
                        if (j == pos) {
                            const float4* sn = (const float4*)(kn + half * 32);
                            float4* dsn = (float4*)(okeys + off + (size_t)pos * DD + half * 32);
#pragma unroll
                            for (int i = 0; i < 8; i++) {
                                float4 k4 = sn[i];
                                dsn[i] = k4;
                                int e = half * 32 + 4 * i;
                                sj += k4.x * qs[e] + k4.y * qs[e + 1] + k4.z * qs[e + 2] + k4.w * qs[e + 3];
                            }
                        } else {
                            const f4_* s4 = (const f4_*)(Kc + (size_t)j * DD + half * 32);
#pragma unroll
                            for (int i = 0; i < 8; i++) {
                                f4_ k4 = __builtin_nontemporal_load(s4 + i);
                                int e = half * 32 + 4 * i;
                                sj += k4.x * qs[e] + k4.y * qs[e + 1] + k4.z * qs[e + 2] + k4.w * qs[e + 3];
                            }
                        }
                    }
                    sj += __shfl_xor(sj, 1);
                    if (half == 0) sv[row] = (j < kv) ? sj * 0.125f : -INFINITY;
                }
                __syncthreads();

                if (t < 64) {
                    float v = sv[t];
                    if (t < CROWS - 64) v = fmaxf(v, sv[64 + t]);
#pragma unroll
                    for (int m = 32; m >= 1; m >>= 1) v = fmaxf(v, __shfl_xor(v, m));
                    if (t == 0) bcv[0] = v;
                }
                __syncthreads();
                float mth = bcv[0];
                if (t < CROWS) sv[t] = __expf(sv[t] - mth);
                __syncthreads();
                if (t < 64) {
                    float p = sv[t];
                    if (t < CROWS - 64) p += sv[64 + t];
#pragma unroll
                    for (int m = 32; m >= 1; m >>= 1) p += __shfl_xor(p, m);
                    if (t == 0) bcv[1] = p;
                }

                int d = t & 63, grp = t >> 6;
                float od = 0.f;
                for (int jj = j0 + grp; jj < j0 + CROWS; jj += 4) {
                    if (jj == pos) {
                        float vv = vn[d];
                        ovals[off + (size_t)pos * DD + d] = vv;
                        od += sv[jj - j0] * vv;
                    } else if (jj < kv) {
                        od += sv[jj - j0] * __builtin_nontemporal_load(&Vc[(size_t)jj * DD + d]);
                    }
                }
                __syncthreads();
                red[t] = od; __syncthreads();
                if (t < 64) {
                    float tt = red[t] + red[64 + t] + red[128 + t] + red[192 + t];
                    po[(size_t)idx * 64 + t] = tt;
                }
                if (t == 0) { pm[idx] = mth; psum[idx] = bcv[1]; }
                __syncthreads();
            }
            nbar++; gbar(gq, rank, c, nbar);

            // ---- Ph2: o = combine(partials); tproj = o@pw + pb
            for (int i = t; i < EE; i += 256) {
                int hh = i >> 6, d = i & 63;
                int base = (g * HH + hh) * NCHU;
                float M = -INFINITY;
#pragma unroll
                for (int ch = 0; ch < NCHU; ch++) if (psum[base + ch] > 0.f) M = fmaxf(M, pm[base + ch]);
                float den = 0.f, acc = 0.f;
#pragma unroll
                for (int ch = 0; ch < NCHU; ch++) {
                    float ps = psum[base + ch];
                    if (ps > 0.f) {
                        float f = __expf(pm[base + ch] - M);
                        den += ps * f;
                        acc += po[(size_t)(base + ch) * 64 + d] * f;
                    }
                }
                xl[i] = acc / den;
            }
            __syncthreads();
            for (unsigned u = rank; u < 96; u += c)
                gemmN<8>(xl, EE, pw_l, EE, pb_l, tprojg, u * 8, red);
            nbar++; gbar(gq, rank, c, nbar);

            // ---- Ph3: x2=LN2(hA+tproj); fcbuf = x2@fw + fb ; hB=hA+tproj (distributed)
            ln_row(hAg, tprojg, ln2g + l * EE, ln2b + l * EE, xl, red, bcv);
            for (unsigned u = rank; u < 96; u += c)
                gemmN<32>(xl, EE, fw_l, E4, fb_l, fcbufg, u * 32, red);
            for (unsigned i = rank; i < 96; i += c)
                if (t < 8) { int e = i * 8 + t; hBg[e] = hAg[e] + tprojg[e]; }
            nbar++; gbar(gq, rank, c, nbar);

            // ---- Ph4: tmlp = gelu(fcbuf)@fpw + fpb
            for (int i = t; i < E4; i += 256) xl[i] = gelu_tanh(fcbufg[i]);
            __syncthreads();
            for (unsigned u = rank; u < 96; u += c)
                gemmN<8>(xl, E4, fpw_l, EE, fpb_l, tmlpg, u * 8, red);
            nbar++; gbar(gq, rank, c, nbar);
        }

        // ---- final LN -> xf row g (published device-wide)
        if (rank == 0) {
            ln_row(hBg, tmlpg, lnfg, lnfb, xl, red, bcv);
            for (int i = t; i < EE; i += 256) st_sys(&xf[g * EE + i], xl[i]);
        }
    } else {
        // ================= copy blocks: group-local slice, 8x f4 chunks =========
        unsigned crank = rank - c;
        unsigned ctot = sg - c;
        const f4_* kq = (const f4_*)past_k;
        const f4_* vq = (const f4_*)past_v;
        f4_* ko = (f4_*)okeys;
        f4_* vo = (f4_*)ovals;
        size_t s0 = (size_t)g * SL;
        size_t stride = (size_t)ctot * 2048;
        for (size_t ii = (size_t)crank * 2048 + (size_t)t * 8; ii < SL; ii += stride) {
            size_t i0 = s0 + ii;
            bool isK = i0 < N4HALF;
            size_t j = isK ? i0 : i0 - N4HALF;
            const f4_* src = (isK ? kq : vq) + j;
            f4_* dst = (isK ? ko : vo) + j;
            int r0 = (int)((j >> 4) & (SS - 1));
            int r1 = (int)(((j + 7) >> 4) & (SS - 1));
            if (r0 != pos && r1 != pos) {
                f4_ a0 = __builtin_nontemporal_load(src + 0);
                f4_ a1 = __builtin_nontemporal_load(src + 1);
                f4_ a2 = __builtin_nontemporal_load(src + 2);
                f4_ a3 = __builtin_nontemporal_load(src + 3);
                f4_ a4 = __builtin_nontemporal_load(src + 4);
                f4_ a5 = __builtin_nontemporal_load(src + 5);
                f4_ a6 = __builtin_nontemporal_load(src + 6);
                f4_ a7 = __builtin_nontemporal_load(src + 7);
                __builtin_nontemporal_store(a0, dst + 0);
                __builtin_nontemporal_store(a1, dst + 1);
                __builtin_nontemporal_store(a2, dst + 2);
                __builtin_nontemporal_store(a3, dst + 3);
                __builtin_nontemporal_store(a4, dst + 4);
                __builtin_nontemporal_store(a5, dst + 5);
                __builtin_nontemporal_store(a6, dst + 6);
                __builtin_nontemporal_store(a7, dst + 7);
            } else {
#pragma unroll
                for (int k = 0; k < 8; k++) {
                    int rr = (int)(((j + k) >> 4) & (SS - 1));
                    if (rr != pos) {
                        f4_ v = __builtin_nontemporal_load(src + k);
                        __builtin_nontemporal_store(v, dst + k);
                    }
                }
            }
        }
    }

    // ---- hierarchical final barrier, then logits = xf @ wte^T
    gbar_final(ctrl + 3072, g, sg);

    int vb = blockIdx.x;
    if (vb < 786) {
        for (int i = t; i < BB * EE; i += 256) xl[i] = xf[i];
        __syncthreads();
        int v = vb * 64 + (t >> 2);
        if (v < VV) {
            int el = t & 3;
            const f4_* w = (const f4_*)(wte + (size_t)v * EE);
            float acc[8] = {0, 0, 0, 0, 0, 0, 0, 0};
            for (int i = el; i < 192; i += 4) {
                f4_ w4 = __builtin_nontemporal_load(w + i);
#pragma unroll
                for (int b = 0; b < 8; b++) {
                    float4 xx = ((const float4*)(xl + b * EE))[i];
                    acc[b] += w4.x * xx.x + w4.y * xx.y + w4.z * xx.z + w4.w * xx.w;
                }
            }
#pragma unroll
            for (int b = 0; b < 8; b++) {
                acc[b] += __shfl_xor(acc[b], 1);
                acc[b] += __shfl_xor(acc[b], 2);
            }
            if (el == 0) {
#pragma unroll
                for (int b = 0; b < 8; b++) logits[(size_t)b * VV + v] = acc[b];
            }
        }
    }
}

extern "C" void kernel_launch(void* const* d_in, const int* in_sizes, int n_in,
                              void* d_out, int out_size, void* d_ws, size_t ws_size,
                              hipStream_t stream) {
    const int* ids = (const int*)d_in[0];
    const int* posp = (const int*)d_in[1];
    const float* past_k = (const float*)d_in[2];
    const float* past_v = (const float*)d_in[3];
    const float* wte = (const float*)d_in[4];
    const float* wpe = (const float*)d_in[5];
    const float* ln1g = (const float*)d_in[6];
    const float* ln1b = (const float*)d_in[7];
    const float* aw = (const float*)d_in[8];
    const float* ab = (const float*)d_in[9];
    const float* pw = (const float*)d_in[10];
    const float* pb = (const float*)d_in[11];
    const float* ln2g = (const float*)d_in[12];
    const float* ln2b = (const float*)d_in[13];
    const float* fw = (const float*)d_in[14];
    const float* fb = (const float*)d_in[15];
    const float* fpw = (const float*)d_in[16];
    const float* fpb = (const float*)d_in[17];
    const float* lnfg = (const float*)d_in[18];
    const float* lnfb = (const float*)d_in[19];

    float* logits = (float*)d_out;
    float* okeys = logits + (size_t)BB * VV;
    float* ovals = okeys + (size_t)LL * BB * HH * SS * DD;

    unsigned* ctrl = (unsigned*)d_ws;                 // 16 KB control area
    float* base = (float*)((char*)d_ws + 16384);
    float* hB = base;
    float* hA = hB + BB * EE;
    float* tmlp = hA + BB * EE;
    float* tproj = tmlp + BB * EE;
    float* qkv = tproj + BB * EE;
    float* fcbuf = qkv + BB * E3;
    float* pm = fcbuf + BB * E4;
    float* psum = pm + BB * HH * NCHU;
    float* po = psum + BB * HH * NCHU;
    float* xf = po + (size_t)BB * HH * NCHU * 64;

    hipMemsetAsync(ctrl, 0, 16384, stream);
    k_all<<<GRID_, 256, 0, stream>>>(
        ids, posp, past_k, past_v, wte, wpe, ln1g, ln1b, aw, ab, pw, pb,
        ln2g, ln2b, fw, fb, fpw, fpb, lnfg, lnfb,
        logits, okeys, ovals, ctrl,
        hB, hA, tmlp, tproj, qkv, fcbuf, pm, psum, po, xf);
}

// Round 10
// 1757.933 us; speedup vs baseline: 1.9904x; 1.9904x over previous
//
#include <hip/hip_runtime.h>
#include <hip/hip_bf16.h>

#define LL 12
#define BB 8
#define HH 12
#define EE 768
#define DD 64
#define SS 1024
#define VV 50257
#define E3 2304
#define E4 3072
#define NCH 16
#define CROWS 64
#define KCH 64

#define N4HALF 18874368ull              // float4 per KV buffer (L*B*H*S*D/4)
#define N4TOT  37748736ull              // both buffers
#define NSLICE 60
#define W4 ((N4TOT + NSLICE - 1) / NSLICE)
#define COPYBLK 512

__device__ __forceinline__ float gelu_tanh(float v) {
    float c = 0.7978845608028654f * (v + 0.044715f * v * v * v);
    return 0.5f * v * (1.0f + tanhf(c));
}

// copy one slice of the combined [K|V] cache space, skipping row==pos (attn writes it)
// 4 float4 per thread per pass: loads batched before stores (one HBM round-trip deep)
__device__ __forceinline__ void copy_slice(const float4* __restrict__ kq, const float4* __restrict__ vq,
                                           float4* __restrict__ ko, float4* __restrict__ vo,
                                           int pos, int slice, int blkLocal) {
    size_t base = (size_t)slice * W4;
    size_t end = base + W4;
    if (end > N4TOT) end = N4TOT;
    size_t idx = base + ((size_t)blkLocal * 256 + threadIdx.x) * 4;
    const size_t stride = (size_t)COPYBLK * 256 * 4;
    for (size_t i0 = idx; i0 < end; i0 += stride) {
        float4 v[4];
        bool ok[4];
        size_t off[4];
        bool isK[4];
#pragma unroll
        for (int k = 0; k < 4; k++) {
            size_t i = i0 + k;
            ok[k] = false;
            isK[k] = false;
            off[k] = 0;
            if (i < end) {
                int row = (int)((i >> 4) & (SS - 1));
                if (row != pos) {
                    ok[k] = true;
                    if (i < N4HALF) { isK[k] = true; off[k] = i; v[k] = kq[i]; }
                    else { isK[k] = false; off[k] = i - N4HALF; v[k] = vq[i - N4HALF]; }
                }
            }
        }
#pragma unroll
        for (int k = 0; k < 4; k++) {
            if (ok[k]) {
                if (isK[k]) ko[off[k]] = v[k];
                else vo[off[k]] = v[k];
            }
        }
    }
}

// prologue: embed -> hB, tmlp=0, qkv=attn bias layer0
__global__ void k_pre(const int* __restrict__ ids, const int* __restrict__ posp,
                      const float* __restrict__ wte, const float* __restrict__ wpe,
                      float* __restrict__ hB, float* __restrict__ tmlp,
                      float* __restrict__ qkv, const float* __restrict__ ab0) {
    int blk = blockIdx.x, t = threadIdx.x;
    if (blk < 24) {
        int i = blk * 256 + t;
        int b = i / EE, e = i % EE;
        hB[i] = wte[(size_t)ids[b] * EE + e] + wpe[(size_t)(*posp) * EE + e];
    } else if (blk < 48) {
        int i = (blk - 24) * 256 + t;
        tmlp[i] = 0.f;
    } else {
        int i = (blk - 48) * 256 + t;
        qkv[i] = ab0[i % E3];
    }
}

// per-row LN stats over (h1+h2): 8 rows x 32 lanes
__device__ __forceinline__ void ln_stats(const float* __restrict__ h1, const float* __restrict__ h2,
                                         float* mean, float* rstd) {
    int t = threadIdx.x, r = t >> 5, l = t & 31;
    float s = 0.f, ss = 0.f;
#pragma unroll
    for (int i = 0; i < 24; i++) {
        int e = l + i * 32;
        float v = h1[r * EE + e] + h2[r * EE + e];
        s += v; ss += v * v;
    }
#pragma unroll
    for (int m = 16; m >= 1; m >>= 1) { s += __shfl_xor(s, m); ss += __shfl_xor(ss, m); }
    if (l == 0) {
        float mu = s * (1.f / EE);
        mean[r] = mu;
        rstd[r] = rsqrtf(ss * (1.f / EE) - mu * mu + 1e-5f);
    }
}

// xl[8][64] x W[64 x 64cols] -> atomicAdd out[8][64cols]
__device__ __forceinline__ void gemm_tile(const float (*xl)[KCH], const float* __restrict__ W,
                                          float* __restrict__ out, int e0, int c0, int C) {
    int t = threadIdx.x;
    int c = c0 + (t & 63);
    int r2 = (t >> 6) * 2;
    const float* Wp = W + (size_t)e0 * C + c;
    float a0 = 0.f, a1 = 0.f;
#pragma unroll
    for (int e = 0; e < KCH; e++) {
        float w = Wp[(size_t)e * C];
        a0 += xl[r2][e] * w;
        a1 += xl[r2 + 1][e] * w;
    }
    atomicAdd(&out[(size_t)r2 * C + c], a0);
    atomicAdd(&out[(size_t)(r2 + 1) * C + c], a1);
}

// fused: x = LN(h1+h2); out += x @ W. extras: hWrite=h1+h2 (24), bias init (nBias), copy (COPYBLK)
__global__ void k_ln_gemm(const float* __restrict__ h1, const float* __restrict__ h2,
                          const float* __restrict__ g, const float* __restrict__ bt,
                          const float* __restrict__ W, float* __restrict__ out,
                          int C, int nColBlk,
                          float* __restrict__ hWrite,
                          float* __restrict__ ib, const float* __restrict__ bb, int bC, int nBias,
                          const float4* __restrict__ kq, const float4* __restrict__ vq,
                          float4* __restrict__ ko, float4* __restrict__ vo,
                          const int* __restrict__ posp, int slice) {
    int nMain = 12 * nColBlk;
    int blk = blockIdx.x, t = threadIdx.x;
    if (blk >= nMain) {
        int x = blk - nMain;
        if (x < 24) { int i = x * 256 + t; hWrite[i] = h1[i] + h2[i]; return; }
        x -= 24;
        if (x < nBias) { int i = x * 256 + t; ib[i] = bb[i % bC]; return; }
        copy_slice(kq, vq, ko, vo, *posp, slice, x - nBias);
        return;
    }
    int chunk = blk / nColBlk, colblk = blk % nColBlk;
    int e0 = chunk * KCH, c0 = colblk * 64;
    __shared__ float xl[8][KCH];
    __shared__ float mean[8], rstd[8];
    ln_stats(h1, h2, mean, rstd);
    __syncthreads();
    for (int i = t; i < 8 * KCH; i += 256) {
        int b = i >> 6, l = i & 63, e = e0 + l;
        xl[b][l] = (h1[b * EE + e] + h2[b * EE + e] - mean[b]) * rstd[b] * g[e] + bt[e];
    }
    __syncthreads();
    gemm_tile(xl, W, out, e0, c0, C);
}

// flash-decode attention chunk (+ write new K/V row). extras: fcbuf bias (96), copy
__global__ void k_attn(const float4* __restrict__ kq, const float4* __restrict__ vq,
                       float4* __restrict__ ko, float4* __restrict__ vo, size_t co,
                       const float* __restrict__ qkv,
                       float* __restrict__ pm, float* __restrict__ psum, float* __restrict__ po,
                       const int* __restrict__ posp,
                       float* __restrict__ ib, const float* __restrict__ bb, int slice) {
    const int NMAIN = BB * HH * NCH;
    int blk = blockIdx.x, t = threadIdx.x;
    if (blk >= NMAIN) {
        int x = blk - NMAIN;
        if (x < 96) { int i = x * 256 + t; ib[i] = bb[i % E4]; return; }
        copy_slice(kq, vq, ko, vo, *posp, slice, x - 96);
        return;
    }
    int ch = blk & (NCH - 1), bh = blk >> 4;
    int b = bh / HH, hh = bh % HH;
    int pos = *posp, kv = pos + 1;
    int j0 = ch * CROWS;
    int idx = bh * NCH + ch;
    if (j0 >= kv) { if (t == 0) psum[idx] = 0.f; return; }

    const size_t off = co + (size_t)bh * SS * DD;
    const float* Kc = (const float*)kq + off;
    const float* Vc = (const float*)vq + off;
    float* Ko = (float*)ko + off;
    float* Vo = (float*)vo + off;
    const float* qn = qkv + (size_t)b * E3 + hh * DD;
    const float* kn = qn + EE;
    const float* vn = qn + 2 * EE;

    __shared__ float qs[DD], s[CROWS], red[256], bc[2];
    if (t < DD) qs[t] = qn[t];
    __syncthreads();

    // K pass: 4 threads per row (16 floats each)
    int row = t >> 2, q = t & 3;
    int j = j0 + row;
    float sj = 0.f;
    if (j < kv) {
        const float4* s4 = (const float4*)(((j == pos) ? kn : (Kc + (size_t)j * DD)) + q * 16);
#pragma unroll
        for (int i = 0; i < 4; i++) {
            float4 k4 = s4[i];
            int e = q * 16 + 4 * i;
            sj += k4.x * qs[e] + k4.y * qs[e + 1] + k4.z * qs[e + 2] + k4.w * qs[e + 3];
        }
    }
    sj += __shfl_xor(sj, 1);
    sj += __shfl_xor(sj, 2);
    if (j == pos) {  // write new K row
        float4* dst = (float4*)(Ko + (size_t)pos * DD + q * 16);
        const float4* sn = (const float4*)(kn + q * 16);
#pragma unroll
        for (int i = 0; i < 4; i++) dst[i] = sn[i];
    }
    if (q == 0) s[row] = (j < kv) ? sj * 0.125f : -INFINITY;
    __syncthreads();

    if (t < 64) {
        float v = s[t];
#pragma unroll
        for (int m = 1; m <= 32; m <<= 1) v = fmaxf(v, __shfl_xor(v, m));
        if (t == 0) bc[0] = v;
    }
    __syncthreads();
    float m = bc[0];
    if (t < 64) s[t] = __expf(s[t] - m);
    __syncthreads();
    if (t < 64) {
        float p = s[t];
#pragma unroll
        for (int mm = 1; mm <= 32; mm <<= 1) p += __shfl_xor(p, mm);
        if (t == 0) bc[1] = p;
    }

    // V pass (fully unrolled: 16 independent loads in flight)
    int d = t & 63, grp = t >> 6;
    float od = 0.f;
#pragma unroll
    for (int ii = 0; ii < CROWS / 4; ii++) {
        int jj = j0 + grp + ii * 4;
        if (jj == pos) {
            float vv = vn[d];
            Vo[(size_t)pos * DD + d] = vv;
            od += s[jj - j0] * vv;
        } else if (jj < kv) {
            od += s[jj - j0] * Vc[(size_t)jj * DD + d];
        }
    }
    __syncthreads();
    red[t] = od;
    __syncthreads();
    if (t < 64) {
        float tt = red[t] + red[64 + t] + red[128 + t] + red[192 + t];
        po[(size_t)idx * 64 + t] = tt;
    }
    if (t == 0) { pm[idx] = m; psum[idx] = bc[1]; }
}

// fused: o = combine(partials); tproj += o @ proj_w. extras: tmlp=fcp bias (24), copy
__global__ void k_comb_gemm(const float* __restrict__ pm, const float* __restrict__ psum,
                            const float* __restrict__ po,
                            const float* __restrict__ W, float* __restrict__ out,
                            float* __restrict__ ib, const float* __restrict__ bb,
                            const float4* __restrict__ kq, const float4* __restrict__ vq,
                            float4* __restrict__ ko, float4* __restrict__ vo,
                            const int* __restrict__ posp, int slice) {
    const int nMain = 12 * 12;
    int blk = blockIdx.x, t = threadIdx.x;
    if (blk >= nMain) {
        int x = blk - nMain;
        if (x < 24) { int i = x * 256 + t; ib[i] = bb[i % EE]; return; }
        copy_slice(kq, vq, ko, vo, *posp, slice, x - 24);
        return;
    }
    int chunk = blk / 12, colblk = blk % 12;
    int e0 = chunk * KCH, c0 = colblk * 64;
    __shared__ float xl[8][KCH];
    for (int i = t; i < 8 * KCH; i += 256) {
        int b = i >> 6, l = i & 63;
        int e = e0 + l;
        int hh = e >> 6, d = e & 63;
        int bh = b * HH + hh;
        float M = -INFINITY;
#pragma unroll
        for (int ch = 0; ch < NCH; ch++) {
            int idx = bh * NCH + ch;
            if (psum[idx] > 0.f) M = fmaxf(M, pm[idx]);
        }
        float den = 0.f, acc = 0.f;
#pragma unroll
        for (int ch = 0; ch < NCH; ch++) {
            int idx = bh * NCH + ch;
            float ps = psum[idx];
            if (ps > 0.f) {
                float f = __expf(pm[idx] - M);
                den += ps * f;
                acc += po[(size_t)idx * 64 + d] * f;
            }
        }
        xl[b][l] = acc / den;
    }
    __syncthreads();
    gemm_tile(xl, W, out, e0, c0, EE);
}

// fused: tmlp += gelu(fcbuf) @ fcp_w. extras: qkv = next-layer attn bias (nBias), copy
__global__ void k_gelu_gemm(const float* __restrict__ fc, const float* __restrict__ W,
                            float* __restrict__ out,
                            float* __restrict__ ib, const float* __restrict__ bb, int nBias,
                            const float4* __restrict__ kq, const float4* __restrict__ vq,
                            float4* __restrict__ ko, float4* __restrict__ vo,
                            const int* __restrict__ posp, int slice) {
    const int nMain = 48 * 12;
    int blk = blockIdx.x, t = threadIdx.x;
    if (blk >= nMain) {
        int x = blk - nMain;
        if (x < nBias) { int i = x * 256 + t; ib[i] = bb[i % E3]; return; }
        copy_slice(kq, vq, ko, vo, *posp, slice, x - nBias);
        return;
    }
    int chunk = blk / 12, colblk = blk % 12;
    int e0 = chunk * KCH, c0 = colblk * 64;
    __shared__ float xl[8][KCH];
    for (int i = t; i < 8 * KCH; i += 256) {
        int b = i >> 6, l = i & 63;
        xl[b][l] = gelu_tanh(fc[(size_t)b * E4 + e0 + l]);
    }
    __syncthreads();
    gemm_tile(xl, W, out, e0, c0, EE);
}

// fused final LN + logits = lnf(hB+tmlp) @ wte^T
__global__ void k_logits(const float* __restrict__ h1, const float* __restrict__ h2,
                         const float* __restrict__ g, const float* __restrict__ bt,
                         const float* __restrict__ wte, float* __restrict__ logits) {
    __shared__ float xl[8][768];
    __shared__ float mean[8], rstd[8];
    ln_stats(h1, h2, mean, rstd);
    __syncthreads();
    for (int i = threadIdx.x; i < 8 * 768; i += 256) {
        int b = i / 768, e = i % 768;
        xl[b][e] = (h1[i] + h2[i] - mean[b]) * rstd[b] * g[e] + bt[e];
    }
    __syncthreads();
    int t = threadIdx.x;
    int v = blockIdx.x * 64 + (t >> 2);
    if (v >= VV) return;
    int el = t & 3;
    const float4* w = (const float4*)(wte + (size_t)v * EE);
    float acc[8] = {0, 0, 0, 0, 0, 0, 0, 0};
    for (int i = el; i < 192; i += 4) {
        float4 w4 = w[i];
#pragma unroll
        for (int b = 0; b < 8; b++) {
            float4 xx = ((const float4*)xl[b])[i];
            acc[b] += w4.x * xx.x + w4.y * xx.y + w4.z * xx.z + w4.w * xx.w;
        }
    }
#pragma unroll
    for (int b = 0; b < 8; b++) {
        acc[b] += __shfl_xor(acc[b], 1);
        acc[b] += __shfl_xor(acc[b], 2);
    }
    if (el == 0) {
#pragma unroll
        for (int b = 0; b < 8; b++) logits[(size_t)b * VV + v] = acc[b];
    }
}

extern "C" void kernel_launch(void* const* d_in, const int* in_sizes, int n_in,
                              void* d_out, int out_size, void* d_ws, size_t ws_size,
                              hipStream_t stream) {
    const int* ids = (const int*)d_in[0];
    const int* posp = (const int*)d_in[1];
    const float4* past_k = (const float4*)d_in[2];
    const float4* past_v = (const float4*)d_in[3];
    const float* wte = (const float*)d_in[4];
    const float* wpe = (const float*)d_in[5];
    const float* ln1g = (const float*)d_in[6];
    const float* ln1b = (const float*)d_in[7];
    const float* aw = (const float*)d_in[8];
    const float* ab = (const float*)d_in[9];
    const float* pw = (const float*)d_in[10];
    const float* pb = (const float*)d_in[11];
    const float* ln2g = (const float*)d_in[12];
    const float* ln2b = (const float*)d_in[13];
    const float* fw = (const float*)d_in[14];
    const float* fb = (const float*)d_in[15];
    const float* fpw = (const float*)d_in[16];
    const float* fpb = (const float*)d_in[17];
    const float* lnfg = (const float*)d_in[18];
    const float* lnfb = (const float*)d_in[19];

    float* logits = (float*)d_out;
    float4* okeys = (float4*)(logits + (size_t)BB * VV);
    float4* ovals = okeys + N4HALF;

    float* ws = (float*)d_ws;
    float* hB = ws;
    float* hA = hB + BB * EE;
    float* tmlp = hA + BB * EE;
    float* tproj = tmlp + BB * EE;
    float* qkv = tproj + BB * EE;
    float* fcbuf = qkv + BB * E3;
    float* pm = fcbuf + BB * E4;
    float* psum = pm + BB * HH * NCH;
    float* po = psum + BB * HH * NCH;

    k_pre<<<120, 256, 0, stream>>>(ids, posp, wte, wpe, hB, tmlp, qkv, ab);

    for (int l = 0; l < LL; l++) {
        size_t co = (size_t)l * BB * HH * SS * DD;
        int sl = 5 * l;
        // x=LN1(hB+tmlp); qkv += x@aw ; hA=hB+tmlp ; tproj=pb ; copy slice
        k_ln_gemm<<<12 * 36 + 24 + 24 + COPYBLK, 256, 0, stream>>>(
            hB, tmlp, ln1g + l * EE, ln1b + l * EE, aw + (size_t)l * EE * E3, qkv,
            E3, 36, hA, tproj, pb + (size_t)l * EE, EE, 24,
            past_k, past_v, okeys, ovals, posp, sl + 0);
        // attention partials (+ new K/V row) ; fcbuf=fb ; copy slice
        k_attn<<<BB * HH * NCH + 96 + COPYBLK, 256, 0, stream>>>(
            past_k, past_v, okeys, ovals, co,
            qkv, pm, psum, po, posp, fcbuf, fb + (size_t)l * E4, sl + 1);
        // tproj += combine(partials)@pw ; tmlp=fpb ; copy slice
        k_comb_gemm<<<12 * 12 + 24 + COPYBLK, 256, 0, stream>>>(
            pm, psum, po, pw + (size_t)l * EE * EE, tproj, tmlp, fpb + (size_t)l * EE,
            past_k, past_v, okeys, ovals, posp, sl + 2);
        // x2=LN2(hA+tproj); fcbuf += x2@fw ; hB=hA+tproj ; copy slice
        k_ln_gemm<<<12 * 48 + 24 + 0 + COPYBLK, 256, 0, stream>>>(
            hA, tproj, ln2g + l * EE, ln2b + l * EE, fw + (size_t)l * EE * E4, fcbuf,
            E4, 48, hB, nullptr, nullptr, 1, 0,
            past_k, past_v, okeys, ovals, posp, sl + 3);
        // tmlp += gelu(fcbuf)@fpw ; qkv=ab[l+1] (if any) ; copy slice
        int nBias = (l < LL - 1) ? 72 : 0;
        k_gelu_gemm<<<48 * 12 + ((l < LL - 1) ? 72 : 0) + COPYBLK, 256, 0, stream>>>(
            fcbuf, fpw + (size_t)l * E4 * EE, tmlp, qkv, ab + (size_t)(l + 1) * E3, nBias,
            past_k, past_v, okeys, ovals, posp, sl + 4);
    }
    // logits = lnf(hB+tmlp) @ wte^T
    k_logits<<<(VV + 63) / 64, 256, 0, stream>>>(hB, tmlp, lnfg, lnfb, wte, logits);
}

// Round 11
// 1752.421 us; speedup vs baseline: 1.9966x; 1.0031x over previous
//
#include <hip/hip_runtime.h>
#include <hip/hip_bf16.h>

#define LL 12
#define BB 8
#define HH 12
#define EE 768
#define DD 64
#define SS 1024
#define VV 50257
#define E3 2304
#define E4 3072
#define NCH 16
#define CROWS 64
#define KCH 64

#define N4HALF 18874368ull              // float4 per KV buffer (L*B*H*S*D/4)
#define N4TOT  37748736ull              // both buffers
#define NSLICE 60
#define W4 ((N4TOT + NSLICE - 1) / NSLICE)
#define COPYBLK 512

__device__ __forceinline__ float gelu_tanh(float v) {
    float c = 0.7978845608028654f * (v + 0.044715f * v * v * v);
    return 0.5f * v * (1.0f + tanhf(c));
}

// copy one slice of the combined [K|V] cache space, skipping row==pos (attn writes it).
// 4-deep MLP with lane-consecutive addressing: element k for this thread is at
// i0 + k*COPYBLK*256, so every load/store instruction stays fully coalesced.
__device__ __forceinline__ void copy_slice(const float4* __restrict__ kq, const float4* __restrict__ vq,
                                           float4* __restrict__ ko, float4* __restrict__ vo,
                                           int pos, int slice, int blkLocal) {
    size_t base = (size_t)slice * W4;
    size_t end = base + W4;
    if (end > N4TOT) end = N4TOT;
    const size_t lane = (size_t)blkLocal * 256 + threadIdx.x;   // 0..131071
    const size_t step = (size_t)COPYBLK * 256;                  // 131072 float4
    for (size_t i0 = base + lane; i0 < end; i0 += step * 4) {
        float4 v[4];
        bool ok[4];
#pragma unroll
        for (int k = 0; k < 4; k++) {
            size_t i = i0 + (size_t)k * step;
            ok[k] = false;
            if (i < end) {
                int row = (int)((i >> 4) & (SS - 1));
                if (row != pos) {
                    ok[k] = true;
                    v[k] = (i < N4HALF) ? kq[i] : vq[i - N4HALF];
                }
            }
        }
#pragma unroll
        for (int k = 0; k < 4; k++) {
            if (ok[k]) {
                size_t i = i0 + (size_t)k * step;
                if (i < N4HALF) ko[i] = v[k];
                else vo[i - N4HALF] = v[k];
            }
        }
    }
}

// prologue: embed -> hB, tmlp=0, qkv=attn bias layer0
__global__ void k_pre(const int* __restrict__ ids, const int* __restrict__ posp,
                      const float* __restrict__ wte, const float* __restrict__ wpe,
                      float* __restrict__ hB, float* __restrict__ tmlp,
                      float* __restrict__ qkv, const float* __restrict__ ab0) {
    int blk = blockIdx.x, t = threadIdx.x;
    if (blk < 24) {
        int i = blk * 256 + t;
        int b = i / EE, e = i % EE;
        hB[i] = wte[(size_t)ids[b] * EE + e] + wpe[(size_t)(*posp) * EE + e];
    } else if (blk < 48) {
        int i = (blk - 24) * 256 + t;
        tmlp[i] = 0.f;
    } else {
        int i = (blk - 48) * 256 + t;
        qkv[i] = ab0[i % E3];
    }
}

// per-row LN stats over (h1+h2): 8 rows x 32 lanes
__device__ __forceinline__ void ln_stats(const float* __restrict__ h1, const float* __restrict__ h2,
                                         float* mean, float* rstd) {
    int t = threadIdx.x, r = t >> 5, l = t & 31;
    float s = 0.f, ss = 0.f;
#pragma unroll
    for (int i = 0; i < 24; i++) {
        int e = l + i * 32;
        float v = h1[r * EE + e] + h2[r * EE + e];
        s += v; ss += v * v;
    }
#pragma unroll
    for (int m = 16; m >= 1; m >>= 1) { s += __shfl_xor(s, m); ss += __shfl_xor(ss, m); }
    if (l == 0) {
        float mu = s * (1.f / EE);
        mean[r] = mu;
        rstd[r] = rsqrtf(ss * (1.f / EE) - mu * mu + 1e-5f);
    }
}

// xl[8][64] x W[64 x 64cols] -> atomicAdd out[8][64cols]
__device__ __forceinline__ void gemm_tile(const float (*xl)[KCH], const float* __restrict__ W,
                                          float* __restrict__ out, int e0, int c0, int C) {
    int t = threadIdx.x;
    int c = c0 + (t & 63);
    int r2 = (t >> 6) * 2;
    const float* Wp = W + (size_t)e0 * C + c;
    float a0 = 0.f, a1 = 0.f;
#pragma unroll
    for (int e = 0; e < KCH; e++) {
        float w = Wp[(size_t)e * C];
        a0 += xl[r2][e] * w;
        a1 += xl[r2 + 1][e] * w;
    }
    atomicAdd(&out[(size_t)r2 * C + c], a0);
    atomicAdd(&out[(size_t)(r2 + 1) * C + c], a1);
}

// fused: x = LN(h1+h2); out += x @ W. extras: hWrite=h1+h2 (24), bias init (nBias), copy (COPYBLK)
__global__ void k_ln_gemm(const float* __restrict__ h1, const float* __restrict__ h2,
                          const float* __restrict__ g, const float* __restrict__ bt,
                          const float* __restrict__ W, float* __restrict__ out,
                          int C, int nColBlk,
                          float* __restrict__ hWrite,
                          float* __restrict__ ib, const float* __restrict__ bb, int bC, int nBias,
                          const float4* __restrict__ kq, const float4* __restrict__ vq,
                          float4* __restrict__ ko, float4* __restrict__ vo,
                          const int* __restrict__ posp, int slice) {
    int nMain = 12 * nColBlk;
    int blk = blockIdx.x, t = threadIdx.x;
    if (blk >= nMain) {
        int x = blk - nMain;
        if (x < 24) { int i = x * 256 + t; hWrite[i] = h1[i] + h2[i]; return; }
        x -= 24;
        if (x < nBias) { int i = x * 256 + t; ib[i] = bb[i % bC]; return; }
        copy_slice(kq, vq, ko, vo, *posp, slice, x - nBias);
        return;
    }
    int chunk = blk / nColBlk, colblk = blk % nColBlk;
    int e0 = chunk * KCH, c0 = colblk * 64;
    __shared__ float xl[8][KCH];
    __shared__ float mean[8], rstd[8];
    ln_stats(h1, h2, mean, rstd);
    __syncthreads();
    for (int i = t; i < 8 * KCH; i += 256) {
        int b = i >> 6, l = i & 63, e = e0 + l;
        xl[b][l] = (h1[b * EE + e] + h2[b * EE + e] - mean[b]) * rstd[b] * g[e] + bt[e];
    }
    __syncthreads();
    gemm_tile(xl, W, out, e0, c0, C);
}

// flash-decode attention chunk (+ write new K/V row). extras: fcbuf bias (96), copy
__global__ void k_attn(const float4* __restrict__ kq, const float4* __restrict__ vq,
                       float4* __restrict__ ko, float4* __restrict__ vo, size_t co,
                       const float* __restrict__ qkv,
                       float* __restrict__ pm, float* __restrict__ psum, float* __restrict__ po,
                       const int* __restrict__ posp,
                       float* __restrict__ ib, const float* __restrict__ bb, int slice) {
    const int NMAIN = BB * HH * NCH;
    int blk = blockIdx.x, t = threadIdx.x;
    if (blk >= NMAIN) {
        int x = blk - NMAIN;
        if (x < 96) { int i = x * 256 + t; ib[i] = bb[i % E4]; return; }
        copy_slice(kq, vq, ko, vo, *posp, slice, x - 96);
        return;
    }
    int ch = blk & (NCH - 1), bh = blk >> 4;
    int b = bh / HH, hh = bh % HH;
    int pos = *posp, kv = pos + 1;
    int j0 = ch * CROWS;
    int idx = bh * NCH + ch;
    if (j0 >= kv) { if (t == 0) psum[idx] = 0.f; return; }

    const size_t off = co + (size_t)bh * SS * DD;
    const float* Kc = (const float*)kq + off;
    const float* Vc = (const float*)vq + off;
    float* Ko = (float*)ko + off;
    float* Vo = (float*)vo + off;
    const float* qn = qkv + (size_t)b * E3 + hh * DD;
    const float* kn = qn + EE;
    const float* vn = qn + 2 * EE;

    __shared__ float qs[DD], s[CROWS], red[256], bc[2];
    if (t < DD) qs[t] = qn[t];
    __syncthreads();

    // K pass: 4 threads per row (16 floats each)
    int row = t >> 2, q = t & 3;
    int j = j0 + row;
    float sj = 0.f;
    if (j < kv) {
        const float4* s4 = (const float4*)(((j == pos) ? kn : (Kc + (size_t)j * DD)) + q * 16);
#pragma unroll
        for (int i = 0; i < 4; i++) {
            float4 k4 = s4[i];
            int e = q * 16 + 4 * i;
            sj += k4.x * qs[e] + k4.y * qs[e + 1] + k4.z * qs[e + 2] + k4.w * qs[e + 3];
        }
    }
    sj += __shfl_xor(sj, 1);
    sj += __shfl_xor(sj, 2);
    if (j == pos) {  // write new K row
        float4* dst = (float4*)(Ko + (size_t)pos * DD + q * 16);
        const float4* sn = (const float4*)(kn + q * 16);
#pragma unroll
        for (int i = 0; i < 4; i++) dst[i] = sn[i];
    }
    if (q == 0) s[row] = (j < kv) ? sj * 0.125f : -INFINITY;
    __syncthreads();

    if (t < 64) {
        float v = s[t];
#pragma unroll
        for (int m = 1; m <= 32; m <<= 1) v = fmaxf(v, __shfl_xor(v, m));
        if (t == 0) bc[0] = v;
    }
    __syncthreads();
    float m = bc[0];
    if (t < 64) s[t] = __expf(s[t] - m);
    __syncthreads();
    if (t < 64) {
        float p = s[t];
#pragma unroll
        for (int mm = 1; mm <= 32; mm <<= 1) p += __shfl_xor(p, mm);
        if (t == 0) bc[1] = p;
    }

    // V pass
    int d = t & 63, grp = t >> 6;
    float od = 0.f;
    for (int jj = j0 + grp; jj < j0 + CROWS; jj += 4) {
        if (jj == pos) {
            float vv = vn[d];
            Vo[(size_t)pos * DD + d] = vv;
            od += s[jj - j0] * vv;
        } else if (jj < kv) {
            od += s[jj - j0] * Vc[(size_t)jj * DD + d];
        }
    }
    __syncthreads();
    red[t] = od;
    __syncthreads();
    if (t < 64) {
        float tt = red[t] + red[64 + t] + red[128 + t] + red[192 + t];
        po[(size_t)idx * 64 + t] = tt;
    }
    if (t == 0) { pm[idx] = m; psum[idx] = bc[1]; }
}

// fused: o = combine(partials); tproj += o @ proj_w. extras: tmlp=fcp bias (24), copy
__global__ void k_comb_gemm(const float* __restrict__ pm, const float* __restrict__ psum,
                            const float* __restrict__ po,
                            const float* __restrict__ W, float* __restrict__ out,
                            float* __restrict__ ib, const float* __restrict__ bb,
                            const float4* __restrict__ kq, const float4* __restrict__ vq,
                            float4* __restrict__ ko, float4* __restrict__ vo,
                            const int* __restrict__ posp, int slice) {
    const int nMain = 12 * 12;
    int blk = blockIdx.x, t = threadIdx.x;
    if (blk >= nMain) {
        int x = blk - nMain;
        if (x < 24) { int i = x * 256 + t; ib[i] = bb[i % EE]; return; }
        copy_slice(kq, vq, ko, vo, *posp, slice, x - 24);
        return;
    }
    int chunk = blk / 12, colblk = blk % 12;
    int e0 = chunk * KCH, c0 = colblk * 64;
    __shared__ float xl[8][KCH];
    for (int i = t; i < 8 * KCH; i += 256) {
        int b = i >> 6, l = i & 63;
        int e = e0 + l;
        int hh = e >> 6, d = e & 63;
        int bh = b * HH + hh;
        float M = -INFINITY;
#pragma unroll
        for (int ch = 0; ch < NCH; ch++) {
            int idx = bh * NCH + ch;
            if (psum[idx] > 0.f) M = fmaxf(M, pm[idx]);
        }
        float den = 0.f, acc = 0.f;
#pragma unroll
        for (int ch = 0; ch < NCH; ch++) {
            int idx = bh * NCH + ch;
            float ps = psum[idx];
            if (ps > 0.f) {
                float f = __expf(pm[idx] - M);
                den += ps * f;
                acc += po[(size_t)idx * 64 + d] * f;
            }
        }
        xl[b][l] = acc / den;
    }
    __syncthreads();
    gemm_tile(xl, W, out, e0, c0, EE);
}

// fused: tmlp += gelu(fcbuf) @ fcp_w. extras: qkv = next-layer attn bias (nBias), copy
__global__ void k_gelu_gemm(const float* __restrict__ fc, const float* __restrict__ W,
                            float* __restrict__ out,
                            float* __restrict__ ib, const float* __restrict__ bb, int nBias,
                            const float4* __restrict__ kq, const float4* __restrict__ vq,
                            float4* __restrict__ ko, float4* __restrict__ vo,
                            const int* __restrict__ posp, int slice) {
    const int nMain = 48 * 12;
    int blk = blockIdx.x, t = threadIdx.x;
    if (blk >= nMain) {
        int x = blk - nMain;
        if (x < nBias) { int i = x * 256 + t; ib[i] = bb[i % E3]; return; }
        copy_slice(kq, vq, ko, vo, *posp, slice, x - nBias);
        return;
    }
    int chunk = blk / 12, colblk = blk % 12;
    int e0 = chunk * KCH, c0 = colblk * 64;
    __shared__ float xl[8][KCH];
    for (int i = t; i < 8 * KCH; i += 256) {
        int b = i >> 6, l = i & 63;
        xl[b][l] = gelu_tanh(fc[(size_t)b * E4 + e0 + l]);
    }
    __syncthreads();
    gemm_tile(xl, W, out, e0, c0, EE);
}

// fused final LN + logits = lnf(hB+tmlp) @ wte^T
__global__ void k_logits(const float* __restrict__ h1, const float* __restrict__ h2,
                         const float* __restrict__ g, const float* __restrict__ bt,
                         const float* __restrict__ wte, float* __restrict__ logits) {
    __shared__ float xl[8][768];
    __shared__ float mean[8], rstd[8];
    ln_stats(h1, h2, mean, rstd);
    __syncthreads();
    for (int i = threadIdx.x; i < 8 * 768; i += 256) {
        int b = i / 768, e = i % 768;
        xl[b][e] = (h1[i] + h2[i] - mean[b]) * rstd[b] * g[e] + bt[e];
    }
    __syncthreads();
    int t = threadIdx.x;
    int v = blockIdx.x * 64 + (t >> 2);
    if (v >= VV) return;
    int el = t & 3;
    const float4* w = (const float4*)(wte + (size_t)v * EE);
    float acc[8] = {0, 0, 0, 0, 0, 0, 0, 0};
    for (int i = el; i < 192; i += 4) {
        float4 w4 = w[i];
#pragma unroll
        for (int b = 0; b < 8; b++) {
            float4 xx = ((const float4*)xl[b])[i];
            acc[b] += w4.x * xx.x + w4.y * xx.y + w4.z * xx.z + w4.w * xx.w;
        }
    }
#pragma unroll
    for (int b = 0; b < 8; b++) {
        acc[b] += __shfl_xor(acc[b], 1);
        acc[b] += __shfl_xor(acc[b], 2);
    }
    if (el == 0) {
#pragma unroll
        for (int b = 0; b < 8; b++) logits[(size_t)b * VV + v] = acc[b];
    }
}

extern "C" void kernel_launch(void* const* d_in, const int* in_sizes, int n_in,
                              void* d_out, int out_size, void* d_ws, size_t ws_size,
                              hipStream_t stream) {
    const int* ids = (const int*)d_in[0];
    const int* posp = (const int*)d_in[1];
    const float4* past_k = (const float4*)d_in[2];
    const float4* past_v = (const float4*)d_in[3];
    const float* wte = (const float*)d_in[4];
    const float* wpe = (const float*)d_in[5];
    const float* ln1g = (const float*)d_in[6];
    const float* ln1b = (const float*)d_in[7];
    const float* aw = (const float*)d_in[8];
    const float* ab = (const float*)d_in[9];
    const float* pw = (const float*)d_in[10];
    const float* pb = (const float*)d_in[11];
    const float* ln2g = (const float*)d_in[12];
    const float* ln2b = (const float*)d_in[13];
    const float* fw = (const float*)d_in[14];
    const float* fb = (const float*)d_in[15];
    const float* fpw = (const float*)d_in[16];
    const float* fpb = (const float*)d_in[17];
    const float* lnfg = (const float*)d_in[18];
    const float* lnfb = (const float*)d_in[19];

    float* logits = (float*)d_out;
    float4* okeys = (float4*)(logits + (size_t)BB * VV);
    float4* ovals = okeys + N4HALF;

    float* ws = (float*)d_ws;
    float* hB = ws;
    float* hA = hB + BB * EE;
    float* tmlp = hA + BB * EE;
    float* tproj = tmlp + BB * EE;
    float* qkv = tproj + BB * EE;
    float* fcbuf = qkv + BB * E3;
    float* pm = fcbuf + BB * E4;
    float* psum = pm + BB * HH * NCH;
    float* po = psum + BB * HH * NCH;

    k_pre<<<120, 256, 0, stream>>>(ids, posp, wte, wpe, hB, tmlp, qkv, ab);

    for (int l = 0; l < LL; l++) {
        size_t co = (size_t)l * BB * HH * SS * DD;
        int sl = 5 * l;
        // x=LN1(hB+tmlp); qkv += x@aw ; hA=hB+tmlp ; tproj=pb ; copy slice
        k_ln_gemm<<<12 * 36 + 24 + 24 + COPYBLK, 256, 0, stream>>>(
            hB, tmlp, ln1g + l * EE, ln1b + l * EE, aw + (size_t)l * EE * E3, qkv,
            E3, 36, hA, tproj, pb + (size_t)l * EE, EE, 24,
            past_k, past_v, okeys, ovals, posp, sl + 0);
        // attention partials (+ new K/V row) ; fcbuf=fb ; copy slice
        k_attn<<<BB * HH * NCH + 96 + COPYBLK, 256, 0, stream>>>(
            past_k, past_v, okeys, ovals, co,
            qkv, pm, psum, po, posp, fcbuf, fb + (size_t)l * E4, sl + 1);
        // tproj += combine(partials)@pw ; tmlp=fpb ; copy slice
        k_comb_gemm<<<12 * 12 + 24 + COPYBLK, 256, 0, stream>>>(
            pm, psum, po, pw + (size_t)l * EE * EE, tproj, tmlp, fpb + (size_t)l * EE,
            past_k, past_v, okeys, ovals, posp, sl + 2);
        // x2=LN2(hA+tproj); fcbuf += x2@fw ; hB=hA+tproj ; copy slice
        k_ln_gemm<<<12 * 48 + 24 + 0 + COPYBLK, 256, 0, stream>>>(
            hA, tproj, ln2g + l * EE, ln2b + l * EE, fw + (size_t)l * EE * E4, fcbuf,
            E4, 48, hB, nullptr, nullptr, 1, 0,
            past_k, past_v, okeys, ovals, posp, sl + 3);
        // tmlp += gelu(fcbuf)@fpw ; qkv=ab[l+1] (if any) ; copy slice
        int nBias = (l < LL - 1) ? 72 : 0;
        k_gelu_gemm<<<48 * 12 + ((l < LL - 1) ? 72 : 0) + COPYBLK, 256, 0, stream>>>(
            fcbuf, fpw + (size_t)l * E4 * EE, tmlp, qkv, ab + (size_t)(l + 1) * E3, nBias,
            past_k, past_v, okeys, ovals, posp, sl + 4);
    }
    // logits = lnf(hB+tmlp) @ wte^T
    k_logits<<<(VV + 63) / 64, 256, 0, stream>>>(hB, tmlp, lnfg, lnfb, wte, logits);
}

// Round 12
// 817.316 us; speedup vs baseline: 4.2810x; 2.1441x over previous
//
#include <hip/hip_runtime.h>
#include <hip/hip_bf16.h>

#define LL 12
#define BB 8
#define HH 12
#define EE 768
#define DD 64
#define SS 1024
#define VV 50257
#define E3 2304
#define E4 3072
#define NCH 16
#define CROWS 64
#define KCH 64

#define N4HALF 18874368ull              // float4 per KV buffer (L*B*H*S*D/4)
#define N4TOT  37748736ull              // both buffers
#define COPYBLK 512

__device__ __forceinline__ float gelu_tanh(float v) {
    float c = 0.7978845608028654f * (v + 0.044715f * v * v * v);
    return 0.5f * v * (1.0f + tanhf(c));
}

// copy [cb,ce) of the combined [K|V] cache space, skipping row==pos (attn writes it).
// R4-exact 1-deep body: minimal register footprint (this is inlined into every
// phase kernel; extra live state here costs occupancy for ALL blocks).
__device__ __forceinline__ void copy_slice(const float4* __restrict__ kq, const float4* __restrict__ vq,
                                           float4* __restrict__ ko, float4* __restrict__ vo,
                                           int pos, size_t cb, size_t ce, int blkLocal) {
    for (size_t i = cb + (size_t)blkLocal * 256 + threadIdx.x; i < ce; i += (size_t)COPYBLK * 256) {
        int row = (int)((i >> 4) & (SS - 1));
        if (row == pos) continue;
        if (i < N4HALF) ko[i] = kq[i];
        else { size_t j = i - N4HALF; vo[j] = vq[j]; }
    }
}

// prologue: embed -> hB, tmlp=0, qkv=attn bias layer0
__global__ void k_pre(const int* __restrict__ ids, const int* __restrict__ posp,
                      const float* __restrict__ wte, const float* __restrict__ wpe,
                      float* __restrict__ hB, float* __restrict__ tmlp,
                      float* __restrict__ qkv, const float* __restrict__ ab0) {
    int blk = blockIdx.x, t = threadIdx.x;
    if (blk < 24) {
        int i = blk * 256 + t;
        int b = i / EE, e = i % EE;
        hB[i] = wte[(size_t)ids[b] * EE + e] + wpe[(size_t)(*posp) * EE + e];
    } else if (blk < 48) {
        int i = (blk - 24) * 256 + t;
        tmlp[i] = 0.f;
    } else {
        int i = (blk - 48) * 256 + t;
        qkv[i] = ab0[i % E3];
    }
}

// per-row LN stats over (h1+h2): 8 rows x 32 lanes
__device__ __forceinline__ void ln_stats(const float* __restrict__ h1, const float* __restrict__ h2,
                                         float* mean, float* rstd) {
    int t = threadIdx.x, r = t >> 5, l = t & 31;
    float s = 0.f, ss = 0.f;
#pragma unroll
    for (int i = 0; i < 24; i++) {
        int e = l + i * 32;
        float v = h1[r * EE + e] + h2[r * EE + e];
        s += v; ss += v * v;
    }
#pragma unroll
    for (int m = 16; m >= 1; m >>= 1) { s += __shfl_xor(s, m); ss += __shfl_xor(ss, m); }
    if (l == 0) {
        float mu = s * (1.f / EE);
        mean[r] = mu;
        rstd[r] = rsqrtf(ss * (1.f / EE) - mu * mu + 1e-5f);
    }
}

// xl[8][64] x W[64 x 64cols] -> atomicAdd out[8][64cols]
__device__ __forceinline__ void gemm_tile(const float (*xl)[KCH], const float* __restrict__ W,
                                          float* __restrict__ out, int e0, int c0, int C) {
    int t = threadIdx.x;
    int c = c0 + (t & 63);
    int r2 = (t >> 6) * 2;
    const float* Wp = W + (size_t)e0 * C + c;
    float a0 = 0.f, a1 = 0.f;
#pragma unroll
    for (int e = 0; e < KCH; e++) {
        float w = Wp[(size_t)e * C];
        a0 += xl[r2][e] * w;
        a1 += xl[r2 + 1][e] * w;
    }
    atomicAdd(&out[(size_t)r2 * C + c], a0);
    atomicAdd(&out[(size_t)(r2 + 1) * C + c], a1);
}

// fused: x = LN(h1+h2); out += x @ W. extras: hWrite=h1+h2 (24), bias init (nBias), copy (COPYBLK)
__global__ void k_ln_gemm(const float* __restrict__ h1, const float* __restrict__ h2,
                          const float* __restrict__ g, const float* __restrict__ bt,
                          const float* __restrict__ W, float* __restrict__ out,
                          int C, int nColBlk,
                          float* __restrict__ hWrite,
                          float* __restrict__ ib, const float* __restrict__ bb, int bC, int nBias,
                          const float4* __restrict__ kq, const float4* __restrict__ vq,
                          float4* __restrict__ ko, float4* __restrict__ vo,
                          const int* __restrict__ posp, size_t cb, size_t ce) {
    int nMain = 12 * nColBlk;
    int blk = blockIdx.x, t = threadIdx.x;
    if (blk >= nMain) {
        int x = blk - nMain;
        if (x < 24) { int i = x * 256 + t; hWrite[i] = h1[i] + h2[i]; return; }
        x -= 24;
        if (x < nBias) { int i = x * 256 + t; ib[i] = bb[i % bC]; return; }
        copy_slice(kq, vq, ko, vo, *posp, cb, ce, x - nBias);
        return;
    }
    int chunk = blk / nColBlk, colblk = blk % nColBlk;
    int e0 = chunk * KCH, c0 = colblk * 64;
    __shared__ float xl[8][KCH];
    __shared__ float mean[8], rstd[8];
    ln_stats(h1, h2, mean, rstd);
    __syncthreads();
    for (int i = t; i < 8 * KCH; i += 256) {
        int b = i >> 6, l = i & 63, e = e0 + l;
        xl[b][l] = (h1[b * EE + e] + h2[b * EE + e] - mean[b]) * rstd[b] * g[e] + bt[e];
    }
    __syncthreads();
    gemm_tile(xl, W, out, e0, c0, C);
}

// flash-decode attention chunk (+ write new K/V row). extras: fcbuf bias (96), copy
__global__ void k_attn(const float4* __restrict__ kq, const float4* __restrict__ vq,
                       float4* __restrict__ ko, float4* __restrict__ vo, size_t co,
                       const float* __restrict__ qkv,
                       float* __restrict__ pm, float* __restrict__ psum, float* __restrict__ po,
                       const int* __restrict__ posp,
                       float* __restrict__ ib, const float* __restrict__ bb, size_t cb, size_t ce) {
    const int NMAIN = BB * HH * NCH;
    int blk = blockIdx.x, t = threadIdx.x;
    if (blk >= NMAIN) {
        int x = blk - NMAIN;
        if (x < 96) { int i = x * 256 + t; ib[i] = bb[i % E4]; return; }
        copy_slice(kq, vq, ko, vo, *posp, cb, ce, x - 96);
        return;
    }
    int ch = blk & (NCH - 1), bh = blk >> 4;
    int b = bh / HH, hh = bh % HH;
    int pos = *posp, kv = pos + 1;
    int j0 = ch * CROWS;
    int idx = bh * NCH + ch;
    if (j0 >= kv) { if (t == 0) psum[idx] = 0.f; return; }

    const size_t off = co + (size_t)bh * SS * DD;
    const float* Kc = (const float*)kq + off;
    const float* Vc = (const float*)vq + off;
    float* Ko = (float*)ko + off;
    float* Vo = (float*)vo + off;
    const float* qn = qkv + (size_t)b * E3 + hh * DD;
    const float* kn = qn + EE;
    const float* vn = qn + 2 * EE;

    __shared__ float qs[DD], s[CROWS], red[256], bc[2];
    if (t < DD) qs[t] = qn[t];
    __syncthreads();

    // K pass: 4 threads per row (16 floats each)
    int row = t >> 2, q = t & 3;
    int j = j0 + row;
    float sj = 0.f;
    if (j < kv) {
        const float4* s4 = (const float4*)(((j == pos) ? kn : (Kc + (size_t)j * DD)) + q * 16);
#pragma unroll
        for (int i = 0; i < 4; i++) {
            float4 k4 = s4[i];
            int e = q * 16 + 4 * i;
            sj += k4.x * qs[e] + k4.y * qs[e + 1] + k4.z * qs[e + 2] + k4.w * qs[e + 3];
        }
    }
    sj += __shfl_xor(sj, 1);
    sj += __shfl_xor(sj, 2);
    if (j == pos) {  // write new K row
        float4* dst = (float4*)(Ko + (size_t)pos * DD + q * 16);
        const float4* sn = (const float4*)(kn + q * 16);
#pragma unroll
        for (int i = 0; i < 4; i++) dst[i] = sn[i];
    }
    if (q == 0) s[row] = (j < kv) ? sj * 0.125f : -INFINITY;
    __syncthreads();

    if (t < 64) {
        float v = s[t];
#pragma unroll
        for (int m = 1; m <= 32; m <<= 1) v = fmaxf(v, __shfl_xor(v, m));
        if (t == 0) bc[0] = v;
    }
    __syncthreads();
    float m = bc[0];
    if (t < 64) s[t] = __expf(s[t] - m);
    __syncthreads();
    if (t < 64) {
        float p = s[t];
#pragma unroll
        for (int mm = 1; mm <= 32; mm <<= 1) p += __shfl_xor(p, mm);
        if (t == 0) bc[1] = p;
    }

    // V pass
    int d = t & 63, grp = t >> 6;
    float od = 0.f;
    for (int jj = j0 + grp; jj < j0 + CROWS; jj += 4) {
        if (jj == pos) {
            float vv = vn[d];
            Vo[(size_t)pos * DD + d] = vv;
            od += s[jj - j0] * vv;
        } else if (jj < kv) {
            od += s[jj - j0] * Vc[(size_t)jj * DD + d];
        }
    }
    __syncthreads();
    red[t] = od;
    __syncthreads();
    if (t < 64) {
        float tt = red[t] + red[64 + t] + red[128 + t] + red[192 + t];
        po[(size_t)idx * 64 + t] = tt;
    }
    if (t == 0) { pm[idx] = m; psum[idx] = bc[1]; }
}

// fused: o = combine(partials); tproj += o @ proj_w. extras: tmlp=fcp bias (24), copy
__global__ void k_comb_gemm(const float* __restrict__ pm, const float* __restrict__ psum,
                            const float* __restrict__ po,
                            const float* __restrict__ W, float* __restrict__ out,
                            float* __restrict__ ib, const float* __restrict__ bb,
                            const float4* __restrict__ kq, const float4* __restrict__ vq,
                            float4* __restrict__ ko, float4* __restrict__ vo,
                            const int* __restrict__ posp, size_t cb, size_t ce) {
    const int nMain = 12 * 12;
    int blk = blockIdx.x, t = threadIdx.x;
    if (blk >= nMain) {
        int x = blk - nMain;
        if (x < 24) { int i = x * 256 + t; ib[i] = bb[i % EE]; return; }
        copy_slice(kq, vq, ko, vo, *posp, cb, ce, x - 24);
        return;
    }
    int chunk = blk / 12, colblk = blk % 12;
    int e0 = chunk * KCH, c0 = colblk * 64;
    __shared__ float xl[8][KCH];
    for (int i = t; i < 8 * KCH; i += 256) {
        int b = i >> 6, l = i & 63;
        int e = e0 + l;
        int hh = e >> 6, d = e & 63;
        int bh = b * HH + hh;
        float M = -INFINITY;
#pragma unroll
        for (int ch = 0; ch < NCH; ch++) {
            int idx = bh * NCH + ch;
            if (psum[idx] > 0.f) M = fmaxf(M, pm[idx]);
        }
        float den = 0.f, acc = 0.f;
#pragma unroll
        for (int ch = 0; ch < NCH; ch++) {
            int idx = bh * NCH + ch;
            float ps = psum[idx];
            if (ps > 0.f) {
                float f = __expf(pm[idx] - M);
                den += ps * f;
                acc += po[(size_t)idx * 64 + d] * f;
            }
        }
        xl[b][l] = acc / den;
    }
    __syncthreads();
    gemm_tile(xl, W, out, e0, c0, EE);
}

// fused: tmlp += gelu(fcbuf) @ fcp_w. extras: qkv = next-layer attn bias (nBias), copy
__global__ void k_gelu_gemm(const float* __restrict__ fc, const float* __restrict__ W,
                            float* __restrict__ out,
                            float* __restrict__ ib, const float* __restrict__ bb, int nBias,
                            const float4* __restrict__ kq, const float4* __restrict__ vq,
                            float4* __restrict__ ko, float4* __restrict__ vo,
                            const int* __restrict__ posp, size_t cb, size_t ce) {
    const int nMain = 48 * 12;
    int blk = blockIdx.x, t = threadIdx.x;
    if (blk >= nMain) {
        int x = blk - nMain;
        if (x < nBias) { int i = x * 256 + t; ib[i] = bb[i % E3]; return; }
        copy_slice(kq, vq, ko, vo, *posp, cb, ce, x - nBias);
        return;
    }
    int chunk = blk / 12, colblk = blk % 12;
    int e0 = chunk * KCH, c0 = colblk * 64;
    __shared__ float xl[8][KCH];
    for (int i = t; i < 8 * KCH; i += 256) {
        int b = i >> 6, l = i & 63;
        xl[b][l] = gelu_tanh(fc[(size_t)b * E4 + e0 + l]);
    }
    __syncthreads();
    gemm_tile(xl, W, out, e0, c0, EE);
}

// fused final LN + logits = lnf(hB+tmlp) @ wte^T
__global__ void k_logits(const float* __restrict__ h1, const float* __restrict__ h2,
                         const float* __restrict__ g, const float* __restrict__ bt,
                         const float* __restrict__ wte, float* __restrict__ logits) {
    __shared__ float xl[8][768];
    __shared__ float mean[8], rstd[8];
    ln_stats(h1, h2, mean, rstd);
    __syncthreads();
    for (int i = threadIdx.x; i < 8 * 768; i += 256) {
        int b = i / 768, e = i % 768;
        xl[b][e] = (h1[i] + h2[i] - mean[b]) * rstd[b] * g[e] + bt[e];
    }
    __syncthreads();
    int t = threadIdx.x;
    int v = blockIdx.x * 64 + (t >> 2);
    if (v >= VV) return;
    int el = t & 3;
    const float4* w = (const float4*)(wte + (size_t)v * EE);
    float acc[8] = {0, 0, 0, 0, 0, 0, 0, 0};
    for (int i = el; i < 192; i += 4) {
        float4 w4 = w[i];
#pragma unroll
        for (int b = 0; b < 8; b++) {
            float4 xx = ((const float4*)xl[b])[i];
            acc[b] += w4.x * xx.x + w4.y * xx.y + w4.z * xx.z + w4.w * xx.w;
        }
    }
#pragma unroll
    for (int b = 0; b < 8; b++) {
        acc[b] += __shfl_xor(acc[b], 1);
        acc[b] += __shfl_xor(acc[b], 2);
    }
    if (el == 0) {
#pragma unroll
        for (int b = 0; b < 8; b++) logits[(size_t)b * VV + v] = acc[b];
    }
}

extern "C" void kernel_launch(void* const* d_in, const int* in_sizes, int n_in,
                              void* d_out, int out_size, void* d_ws, size_t ws_size,
                              hipStream_t stream) {
    const int* ids = (const int*)d_in[0];
    const int* posp = (const int*)d_in[1];
    const float4* past_k = (const float4*)d_in[2];
    const float4* past_v = (const float4*)d_in[3];
    const float* wte = (const float*)d_in[4];
    const float* wpe = (const float*)d_in[5];
    const float* ln1g = (const float*)d_in[6];
    const float* ln1b = (const float*)d_in[7];
    const float* aw = (const float*)d_in[8];
    const float* ab = (const float*)d_in[9];
    const float* pw = (const float*)d_in[10];
    const float* pb = (const float*)d_in[11];
    const float* ln2g = (const float*)d_in[12];
    const float* ln2b = (const float*)d_in[13];
    const float* fw = (const float*)d_in[14];
    const float* fb = (const float*)d_in[15];
    const float* fpw = (const float*)d_in[16];
    const float* fpb = (const float*)d_in[17];
    const float* lnfg = (const float*)d_in[18];
    const float* lnfb = (const float*)d_in[19];

    float* logits = (float*)d_out;
    float4* okeys = (float4*)(logits + (size_t)BB * VV);
    float4* ovals = okeys + N4HALF;

    float* ws = (float*)d_ws;
    float* hB = ws;
    float* hA = hB + BB * EE;
    float* tmlp = hA + BB * EE;
    float* tproj = tmlp + BB * EE;
    float* qkv = tproj + BB * EE;
    float* fcbuf = qkv + BB * E3;
    float* pm = fcbuf + BB * E4;
    float* psum = pm + BB * HH * NCH;
    float* po = psum + BB * HH * NCH;

    k_pre<<<120, 256, 0, stream>>>(ids, posp, wte, wpe, hB, tmlp, qkv, ab);

    // weighted copy partition: per-layer share N4TOT/12 = 3145728 float4,
    // split across the 5 phase kernels inversely to their compute durations
    // (attn is the longest phase -> smallest copy slice; comb the shortest -> largest)
    static const size_t amt[5] = {692060, 377487, 817890, 629145, 629146};  // sums to 3145728
    size_t cpos = 0;

    for (int l = 0; l < LL; l++) {
        size_t co = (size_t)l * BB * HH * SS * DD;
        size_t b0 = cpos, e0 = b0 + amt[0];
        size_t b1 = e0, e1 = b1 + amt[1];
        size_t b2 = e1, e2 = b2 + amt[2];
        size_t b3 = e2, e3 = b3 + amt[3];
        size_t b4 = e3, e4 = b4 + amt[4];
        cpos = e4;
        // x=LN1(hB+tmlp); qkv += x@aw ; hA=hB+tmlp ; tproj=pb ; copy slice
        k_ln_gemm<<<12 * 36 + 24 + 24 + COPYBLK, 256, 0, stream>>>(
            hB, tmlp, ln1g + l * EE, ln1b + l * EE, aw + (size_t)l * EE * E3, qkv,
            E3, 36, hA, tproj, pb + (size_t)l * EE, EE, 24,
            past_k, past_v, okeys, ovals, posp, b0, e0);
        // attention partials (+ new K/V row) ; fcbuf=fb ; copy slice
        k_attn<<<BB * HH * NCH + 96 + COPYBLK, 256, 0, stream>>>(
            past_k, past_v, okeys, ovals, co,
            qkv, pm, psum, po, posp, fcbuf, fb + (size_t)l * E4, b1, e1);
        // tproj += combine(partials)@pw ; tmlp=fpb ; copy slice
        k_comb_gemm<<<12 * 12 + 24 + COPYBLK, 256, 0, stream>>>(
            pm, psum, po, pw + (size_t)l * EE * EE, tproj, tmlp, fpb + (size_t)l * EE,
            past_k, past_v, okeys, ovals, posp, b2, e2);
        // x2=LN2(hA+tproj); fcbuf += x2@fw ; hB=hA+tproj ; copy slice
        k_ln_gemm<<<12 * 48 + 24 + 0 + COPYBLK, 256, 0, stream>>>(
            hA, tproj, ln2g + l * EE, ln2b + l * EE, fw + (size_t)l * EE * E4, fcbuf,
            E4, 48, hB, nullptr, nullptr, 1, 0,
            past_k, past_v, okeys, ovals, posp, b3, e3);
        // tmlp += gelu(fcbuf)@fpw ; qkv=ab[l+1] (if any) ; copy slice
        int nBias = (l < LL - 1) ? 72 : 0;
        k_gelu_gemm<<<48 * 12 + ((l < LL - 1) ? 72 : 0) + COPYBLK, 256, 0, stream>>>(
            fcbuf, fpw + (size_t)l * E4 * EE, tmlp, qkv, ab + (size_t)(l + 1) * E3, nBias,
            past_k, past_v, okeys, ovals, posp, b4, e4);
    }
    // logits = lnf(hB+tmlp) @ wte^T
    k_logits<<<(VV + 63) / 64, 256, 0, stream>>>(hB, tmlp, lnfg, lnfb, wte, logits);
}